// Round 1
// baseline (445.407 us; speedup 1.0000x reference)
//
#include <hip/hip_runtime.h>
#include <float.h>

// QueryPooling: x[B,L,C] f32, mask[B,L] i32, queries[K,C] f32 -> out[B,K,C] f32
// B=16 L=4096 C=1024 K=16. scale = C^-0.5 = 1/32 exactly.
#define NB 16
#define NL 4096
#define NC 1024
#define NK 16
// scale * log2(e) = 0.03125 * 1.4426950408889634
#define SC2 0.04508422f

__device__ __forceinline__ float4 ld4(const float* p) { return *(const float4*)p; }

// ---------------------------------------------------------------------------
// Kernel 1: fused scores + online softmax + PV over 256-row slabs of L.
// grid = 256 blocks (b = blk/16, l0 = (blk%16)*256), 256 threads.
// Each block streams its slab ONCE from HBM in 16-row LDS-resident sub-chunks.
// Emits per-slab partial O[16][1024] plus per-k (m, s) for a second-pass merge.
//
// Thread decomposition:
//   phase 1 (scores):  kq = tid>>6 (4 query-groups of 4, == wave id),
//                      lg = (tid>>5)&1 (row half), cs = tid&31 (c-split lane).
//                      Q fragment lives in REGISTERS: qr[4][8] float4
//                      (k = kq*4..+4, c-granules cs+32m). 8 ds_read_b128 per
//                      256 FLOP -> VALU-bound.
//   phase 3 (PV):      kg3 = tid>>7 (k half), cg = tid&127 (column group);
//                      accum o0/o1[8] = O[kg3*8..+8][{4cg..+4, 512+4cg..+4}].
// LDS: Xs[16][1028] (pad 4 floats/row -> every access pattern is 8 lanes per
// bank-quad, conflict-free), Wt[l][k], Sr[k][l], m/s/alpha[16]. ~68 KB.
// ---------------------------------------------------------------------------
__global__ __launch_bounds__(256, 1)
void qpool_partial(const float* __restrict__ X, const int* __restrict__ Mk,
                   const float* __restrict__ Q, float* __restrict__ Op,
                   float* __restrict__ MSp) {
  __shared__ float Xs[16 * 1028];
  __shared__ float Wt[16][16];   // Wt[l][k] = unnormalized weight
  __shared__ float Sr[16][16];   // Sr[k][l] = raw score
  __shared__ float mS[16], sS[16], aS[16];

  const int tid = threadIdx.x;
  const int cs  = tid & 31;
  const int lg  = (tid >> 5) & 1;
  const int kq  = tid >> 6;
  const int kg3 = tid >> 7;
  const int cg  = tid & 127;
  const int blk = blockIdx.x;
  const int b   = blk >> 4;
  const int l0  = (blk & 15) << 8;

  const float* Xb = X + (size_t)b * NL * NC;
  const int*   Mb = Mk + (size_t)b * NL;

  // ---- Q fragment into registers (once per block) ----
  float4 qr[4][8];
#pragma unroll
  for (int kk = 0; kk < 4; ++kk)
#pragma unroll
    for (int m = 0; m < 8; ++m)
      qr[kk][m] = ld4(Q + (kq * 4 + kk) * NC + (cs + 32 * m) * 4);

  // ---- PV accumulators ----
  float4 o0[8], o1[8];
#pragma unroll
  for (int kk = 0; kk < 8; ++kk) {
    o0[kk] = make_float4(0.f, 0.f, 0.f, 0.f);
    o1[kk] = make_float4(0.f, 0.f, 0.f, 0.f);
  }

  if (tid < 16) { mS[tid] = -FLT_MAX; sS[tid] = 0.f; }

  // ---- prologue: stage regs for sub-chunk 0 (thread t owns granule t of each row) ----
  float4 st[16];
#pragma unroll
  for (int j = 0; j < 16; ++j)
    st[j] = ld4(Xb + (size_t)(l0 + j) * NC + tid * 4);

  for (int sc = 0; sc < 16; ++sc) {
    __syncthreads();                        // bar1: Xs free (prev PV done)
#pragma unroll
    for (int j = 0; j < 16; ++j)
      *(float4*)(&Xs[j * 1028 + tid * 4]) = st[j];
    __syncthreads();                        // bar2: Xs ready

    const int rb = l0 + (sc + 1) * 16;
    if (sc < 15) {                          // prefetch half 1 (flies during phase 1)
#pragma unroll
      for (int j = 0; j < 8; ++j)
        st[j] = ld4(Xb + (size_t)(rb + j) * NC + tid * 4);
    }

    // ---- phase 1: partial scores, this lane's 32 c-columns ----
    float acc[4][8];
#pragma unroll
    for (int kk = 0; kk < 4; ++kk)
#pragma unroll
      for (int j = 0; j < 8; ++j) acc[kk][j] = 0.f;

#pragma unroll
    for (int m = 0; m < 8; ++m) {
#pragma unroll
      for (int j = 0; j < 8; ++j) {
        const float4 xv = ld4(&Xs[(lg * 8 + j) * 1028 + (cs + 32 * m) * 4]);
#pragma unroll
        for (int kk = 0; kk < 4; ++kk) {
          float a = acc[kk][j];
          a = fmaf(xv.x, qr[kk][m].x, a);
          a = fmaf(xv.y, qr[kk][m].y, a);
          a = fmaf(xv.z, qr[kk][m].z, a);
          a = fmaf(xv.w, qr[kk][m].w, a);
          acc[kk][j] = a;
        }
      }
    }

    // ---- butterfly-reduce over the 32 cs lanes (stays inside each wave) ----
#pragma unroll
    for (int kk = 0; kk < 4; ++kk)
#pragma unroll
      for (int j = 0; j < 8; ++j) {
        float v = acc[kk][j];
        v += __shfl_xor(v, 1, 64);
        v += __shfl_xor(v, 2, 64);
        v += __shfl_xor(v, 4, 64);
        v += __shfl_xor(v, 8, 64);
        v += __shfl_xor(v, 16, 64);
        acc[kk][j] = v;
      }
    if (cs == 0) {
#pragma unroll
      for (int kk = 0; kk < 4; ++kk)
#pragma unroll
        for (int j = 0; j < 8; ++j)
          Sr[kq * 4 + kk][lg * 8 + j] = acc[kk][j];
    }
    __syncthreads();                        // bar3: scores ready

    // ---- online softmax: k = tid>>4, i = tid&15 handles row element l=i ----
    {
      const int k = tid >> 4, i = tid & 15;
      const float sraw = Sr[k][i];
      const int   msk  = Mb[l0 + sc * 16 + i];
      float sval = msk ? sraw : -FLT_MAX;
      float cmax = sval;
      cmax = fmaxf(cmax, __shfl_xor(cmax, 1, 64));
      cmax = fmaxf(cmax, __shfl_xor(cmax, 2, 64));
      cmax = fmaxf(cmax, __shfl_xor(cmax, 4, 64));
      cmax = fmaxf(cmax, __shfl_xor(cmax, 8, 64));
      const float mold = mS[k];
      const float mnew = fmaxf(mold, cmax);
      const float e = msk ? exp2f((sraw - mnew) * SC2) : 0.f;
      float csum = e;
      csum += __shfl_xor(csum, 1, 64);
      csum += __shfl_xor(csum, 2, 64);
      csum += __shfl_xor(csum, 4, 64);
      csum += __shfl_xor(csum, 8, 64);
      Wt[i][k] = e;
      if (i == 0) {
        const float a = exp2f((mold - mnew) * SC2);  // exp2f(0)=1 when both -FLT_MAX
        aS[k] = a;
        mS[k] = mnew;
        sS[k] = sS[k] * a + csum;
      }
    }
    __syncthreads();                        // bar4: Wt/alpha ready

    if (sc < 15) {                          // prefetch half 2 (flies during PV)
#pragma unroll
      for (int j = 8; j < 16; ++j)
        st[j] = ld4(Xb + (size_t)(rb + j) * NC + tid * 4);
    }

    // ---- phase 3: rescale + PV accumulate ----
#pragma unroll
    for (int kk = 0; kk < 8; ++kk) {
      const float a = aS[kg3 * 8 + kk];
      o0[kk].x *= a; o0[kk].y *= a; o0[kk].z *= a; o0[kk].w *= a;
      o1[kk].x *= a; o1[kk].y *= a; o1[kk].z *= a; o1[kk].w *= a;
    }
#pragma unroll
    for (int l = 0; l < 16; ++l) {
      const float4 x0 = ld4(&Xs[l * 1028 + cg * 4]);
      const float4 x1 = ld4(&Xs[l * 1028 + 512 + cg * 4]);
      const float4 w0 = ld4(&Wt[l][kg3 * 8]);
      const float4 w1 = ld4(&Wt[l][kg3 * 8 + 4]);
      float wk[8];
      wk[0] = w0.x; wk[1] = w0.y; wk[2] = w0.z; wk[3] = w0.w;
      wk[4] = w1.x; wk[5] = w1.y; wk[6] = w1.z; wk[7] = w1.w;
#pragma unroll
      for (int kk = 0; kk < 8; ++kk) {
        o0[kk].x = fmaf(wk[kk], x0.x, o0[kk].x);
        o0[kk].y = fmaf(wk[kk], x0.y, o0[kk].y);
        o0[kk].z = fmaf(wk[kk], x0.z, o0[kk].z);
        o0[kk].w = fmaf(wk[kk], x0.w, o0[kk].w);
        o1[kk].x = fmaf(wk[kk], x1.x, o1[kk].x);
        o1[kk].y = fmaf(wk[kk], x1.y, o1[kk].y);
        o1[kk].z = fmaf(wk[kk], x1.z, o1[kk].z);
        o1[kk].w = fmaf(wk[kk], x1.w, o1[kk].w);
      }
    }
  }

  // ---- epilogue: write slab partials ----
  float* Ob = Op + (size_t)blk * NK * NC;
#pragma unroll
  for (int kk = 0; kk < 8; ++kk) {
    const int k = kg3 * 8 + kk;
    *(float4*)(Ob + k * NC + cg * 4)       = o0[kk];
    *(float4*)(Ob + k * NC + 512 + cg * 4) = o1[kk];
  }
  if (tid < 16) {
    MSp[(blk * 16 + tid) * 2]     = mS[tid];
    MSp[(blk * 16 + tid) * 2 + 1] = sS[tid];
  }
}

// ---------------------------------------------------------------------------
// Kernel 2: merge the 16 slab partials per (b,k) with max-rescale + normalize.
// grid = 256 blocks (one per (b,k)), 256 threads (float4 per thread over C).
// All-invalid rows: every slab has s=0 -> denom 0 -> output zeros.
// ---------------------------------------------------------------------------
__global__ __launch_bounds__(256, 1)
void qpool_combine(const float* __restrict__ Op, const float* __restrict__ MSp,
                   float* __restrict__ Out) {
  const int bk = blockIdx.x;
  const int b = bk >> 4, k = bk & 15;
  const int tid = threadIdx.x;

  float m[16], s[16];
  float M = -FLT_MAX;
#pragma unroll
  for (int lb = 0; lb < 16; ++lb) {
    m[lb] = MSp[((b * 16 + lb) * 16 + k) * 2];
    s[lb] = MSp[((b * 16 + lb) * 16 + k) * 2 + 1];
    M = fmaxf(M, m[lb]);
  }
  float denom = 0.f;
  float f[16];
#pragma unroll
  for (int lb = 0; lb < 16; ++lb) {
    f[lb] = exp2f((m[lb] - M) * SC2);
    denom += s[lb] * f[lb];
  }
  float4 acc = make_float4(0.f, 0.f, 0.f, 0.f);
#pragma unroll
  for (int lb = 0; lb < 16; ++lb) {
    const float4 v = ld4(Op + ((size_t)(b * 16 + lb) * 16 + k) * NC + tid * 4);
    acc.x = fmaf(f[lb], v.x, acc.x);
    acc.y = fmaf(f[lb], v.y, acc.y);
    acc.z = fmaf(f[lb], v.z, acc.z);
    acc.w = fmaf(f[lb], v.w, acc.w);
  }
  const float inv = denom > 0.f ? 1.f / denom : 0.f;
  acc.x *= inv; acc.y *= inv; acc.z *= inv; acc.w *= inv;
  *(float4*)(Out + (size_t)bk * NC + tid * 4) = acc;
}

extern "C" void kernel_launch(void* const* d_in, const int* in_sizes, int n_in,
                              void* d_out, int out_size, void* d_ws, size_t ws_size,
                              hipStream_t stream) {
  const float* X  = (const float*)d_in[0];
  const int*   Mk = (const int*)d_in[1];
  const float* Q  = (const float*)d_in[2];
  float* Out = (float*)d_out;

  // workspace: 256 slabs * 16 k * 1024 c partials (16 MB) + 256*16 (m,s) pairs
  float* Op  = (float*)d_ws;
  float* MSp = Op + (size_t)256 * NK * NC;

  qpool_partial<<<256, 256, 0, stream>>>(X, Mk, Q, Op, MSp);
  qpool_combine<<<256, 256, 0, stream>>>(Op, MSp, Out);
}

// Round 2
// 426.564 us; speedup vs baseline: 1.0442x; 1.0442x over previous
//
#include <hip/hip_runtime.h>
#include <float.h>

// QueryPooling: x[B,L,C] f32, mask[B,L] i32, queries[K,C] f32 -> out[B,K,C] f32
// B=16 L=4096 C=1024 K=16. scale = C^-0.5 = 1/32.
#define NB 16
#define NL 4096
#define NC 1024
#define NK 16
// scale * log2(e)
#define SC2 0.04508422f

__device__ __forceinline__ float4 ld4(const float* p) { return *(const float4*)p; }

// async global->LDS, 16B per lane. LDS dest is wave-uniform base + lane*16.
__device__ __forceinline__ void gload16(const float* g, float* l) {
  __builtin_amdgcn_global_load_lds(
      (const __attribute__((address_space(1))) void*)g,
      (__attribute__((address_space(3))) void*)l, 16, 0, 0);
}

#define MEMFENCE() asm volatile("" ::: "memory")
__device__ __forceinline__ void barrier_raw() {
  MEMFENCE();
  __builtin_amdgcn_s_barrier();
  MEMFENCE();
}

// ---------------------------------------------------------------------------
// Kernel 1: fused scores + online softmax + PV, 8-row sub-chunks,
// double-buffered LDS staged via global_load_lds with counted vmcnt.
// template NSC = sub-chunks per slab (slab = NSC*8 rows of L).
//   NSC=16 -> 128-row slabs, grid 512, 2 blocks/CU (the fast path)
//   NSC=32 -> 256-row slabs, grid 256 (ws-size fallback)
// Per sub-chunk barriers: A (buf^1 free) . issue next . vmcnt(8) . B (buf
// staged) . phase1 . C . softmax . D . phase3.
// LDS: Xs[2][8][1024] 64KB + Sr/Wt/Ms/state ~2KB -> 2 blocks/CU fit.
// phase1: wave w owns queries 4w..4w+4, c split over 64 lanes (qr = 64 VGPR),
//         value-splitting butterfly reduces 32 partials in 32 shfls.
// phase3: kg=tid>>7 picks 8 queries, cg=tid&127 picks 8 c-floats; o = 64 VGPR.
// ---------------------------------------------------------------------------
template<int NSC>
__global__ __launch_bounds__(256, 2)
void qpool_partial(const float* __restrict__ X, const int* __restrict__ Mk,
                   const float* __restrict__ Q, float* __restrict__ Op,
                   float* __restrict__ MSp) {
  constexpr int ROWS  = NSC * 8;
  constexpr int SLABS = NL / ROWS;

  __shared__ float Xs[2 * 8 * 1024];
  __shared__ float Sr[128];        // Sr[k*8+i] raw score, k=0..15, i=row 0..7
  __shared__ float Wt[128];        // Wt[i*16+k] unnormalized weight
  __shared__ int   Ms[ROWS];       // slab mask
  __shared__ float mS[16], sS[16], aS[16];

  const int tid  = threadIdx.x;
  const int lane = tid & 63;
  const int wid  = tid >> 6;
  const int kg   = tid >> 7;
  const int cg   = tid & 127;
  const int blk  = blockIdx.x;
  const int b    = blk / SLABS;
  const int l0   = (blk % SLABS) * ROWS;

  const float* Xb = X + (size_t)b * NL * NC;
  const int*   Mb = Mk + (size_t)b * NL;

  // ---- prologue: issue sub-chunk 0 staging (8 vmem ops/thread) ----
  {
    const float* g0 = Xb + (size_t)l0 * NC + (wid * 256 + lane * 4);
#pragma unroll
    for (int j = 0; j < 8; ++j)
      gload16(g0 + (size_t)j * NC, &Xs[j * 1024 + wid * 256]);
  }

  // ---- Q fragment: 4 queries x 16 floats (c-granules lane+64m) = 64 VGPR ----
  float4 qr[4][4];
#pragma unroll
  for (int kk = 0; kk < 4; ++kk)
#pragma unroll
    for (int m = 0; m < 4; ++m)
      qr[kk][m] = ld4(Q + (size_t)(wid * 4 + kk) * NC + (m * 64 + lane) * 4);

  if (tid < ROWS) Ms[tid] = Mb[l0 + tid];
  if (tid < 16) { mS[tid] = -FLT_MAX; sS[tid] = 0.f; }

  float4 o[8][2];
#pragma unroll
  for (int kk = 0; kk < 8; ++kk) {
    o[kk][0] = make_float4(0.f, 0.f, 0.f, 0.f);
    o[kk][1] = make_float4(0.f, 0.f, 0.f, 0.f);
  }

  // butterfly final-value index = bitrev5(lane&31)
  const int vi = ((lane & 1) << 4) | ((lane & 2) << 2) | (lane & 4) |
                 ((lane & 8) >> 2) | ((lane & 16) >> 4);

  for (int sc = 0; sc < NSC; ++sc) {
    const int buf = sc & 1;
    float* Xc = &Xs[buf * 8 * 1024];

    barrier_raw();                                  // A: buf^1's readers done
    if (sc + 1 < NSC) {
      const float* gn = Xb + (size_t)(l0 + (sc + 1) * 8) * NC + (wid * 256 + lane * 4);
      float* ln = &Xs[(buf ^ 1) * 8 * 1024 + wid * 256];
#pragma unroll
      for (int j = 0; j < 8; ++j)
        gload16(gn + (size_t)j * NC, ln + j * 1024);
      asm volatile("s_waitcnt vmcnt(8) lgkmcnt(0)" ::: "memory");  // sc's loads done, next 8 in flight
    } else {
      asm volatile("s_waitcnt vmcnt(0) lgkmcnt(0)" ::: "memory");
    }
    barrier_raw();                                  // B: buf fully staged

    // ---- phase 1: partial scores over this lane's 16 c-columns ----
    float acc[4][8];
#pragma unroll
    for (int kk = 0; kk < 4; ++kk)
#pragma unroll
      for (int j = 0; j < 8; ++j) acc[kk][j] = 0.f;

#pragma unroll
    for (int m = 0; m < 4; ++m) {
#pragma unroll
      for (int j = 0; j < 8; ++j) {
        const float4 xv = ld4(&Xc[j * 1024 + (m * 64 + lane) * 4]);
#pragma unroll
        for (int kk = 0; kk < 4; ++kk) {
          float a = acc[kk][j];
          a = fmaf(xv.x, qr[kk][m].x, a);
          a = fmaf(xv.y, qr[kk][m].y, a);
          a = fmaf(xv.z, qr[kk][m].z, a);
          a = fmaf(xv.w, qr[kk][m].w, a);
          acc[kk][j] = a;
        }
      }
    }

    // ---- value-splitting butterfly: 32 values over 64 lanes, 32 shfls ----
    float v[32];
#pragma unroll
    for (int kk = 0; kk < 4; ++kk)
#pragma unroll
      for (int j = 0; j < 8; ++j) v[kk * 8 + j] = acc[kk][j];
#pragma unroll
    for (int p = 0; p < 5; ++p) {
      const int  mm   = 1 << p;
      const int  half = 16 >> p;
      const bool hi   = (lane & mm) != 0;
#pragma unroll
      for (int i = 0; i < half; ++i) {
        const float send = hi ? v[i] : v[half + i];
        const float keep = hi ? v[half + i] : v[i];
        v[i] = keep + __shfl_xor(send, mm, 64);
      }
    }
    v[0] += __shfl_xor(v[0], 32, 64);
    if (lane < 32) Sr[wid * 32 + vi] = v[0];
    asm volatile("s_waitcnt lgkmcnt(0)" ::: "memory");
    barrier_raw();                                  // C: scores ready

    // ---- online softmax: waves 0-1 (tid<128), k=tid>>3, row i=tid&7 ----
    if (tid < 128) {
      const int k = tid >> 3, i = tid & 7;
      const float sraw = Sr[tid];
      const int   msk  = Ms[sc * 8 + i];
      float cmax = msk ? sraw : -FLT_MAX;
      cmax = fmaxf(cmax, __shfl_xor(cmax, 1, 64));
      cmax = fmaxf(cmax, __shfl_xor(cmax, 2, 64));
      cmax = fmaxf(cmax, __shfl_xor(cmax, 4, 64));
      const float mold = mS[k];
      const float mnew = fmaxf(mold, cmax);
      const float e = msk ? exp2f((sraw - mnew) * SC2) : 0.f;
      float csum = e;
      csum += __shfl_xor(csum, 1, 64);
      csum += __shfl_xor(csum, 2, 64);
      csum += __shfl_xor(csum, 4, 64);
      Wt[i * 16 + k] = e;
      if (i == 0) {
        const float a = exp2f((mold - mnew) * SC2);  // 0 when mold=-inf-ish, 1 when equal
        aS[k] = a;
        mS[k] = mnew;
        sS[k] = sS[k] * a + csum;
      }
    }
    asm volatile("s_waitcnt lgkmcnt(0)" ::: "memory");
    barrier_raw();                                  // D: Wt/aS ready

    // ---- phase 3: rescale + PV accumulate ----
    float a8[8];
#pragma unroll
    for (int kk = 0; kk < 8; ++kk) a8[kk] = aS[kg * 8 + kk];
#pragma unroll
    for (int kk = 0; kk < 8; ++kk) {
      o[kk][0].x *= a8[kk]; o[kk][0].y *= a8[kk]; o[kk][0].z *= a8[kk]; o[kk][0].w *= a8[kk];
      o[kk][1].x *= a8[kk]; o[kk][1].y *= a8[kk]; o[kk][1].z *= a8[kk]; o[kk][1].w *= a8[kk];
    }
#pragma unroll
    for (int l = 0; l < 8; ++l) {
      const float4 x0 = ld4(&Xc[l * 1024 + cg * 4]);
      const float4 x1 = ld4(&Xc[l * 1024 + 512 + cg * 4]);
      const float4 w0 = ld4(&Wt[l * 16 + kg * 8]);
      const float4 w1 = ld4(&Wt[l * 16 + kg * 8 + 4]);
      const float wk[8] = {w0.x, w0.y, w0.z, w0.w, w1.x, w1.y, w1.z, w1.w};
#pragma unroll
      for (int kk = 0; kk < 8; ++kk) {
        o[kk][0].x = fmaf(wk[kk], x0.x, o[kk][0].x);
        o[kk][0].y = fmaf(wk[kk], x0.y, o[kk][0].y);
        o[kk][0].z = fmaf(wk[kk], x0.z, o[kk][0].z);
        o[kk][0].w = fmaf(wk[kk], x0.w, o[kk][0].w);
        o[kk][1].x = fmaf(wk[kk], x1.x, o[kk][1].x);
        o[kk][1].y = fmaf(wk[kk], x1.y, o[kk][1].y);
        o[kk][1].z = fmaf(wk[kk], x1.z, o[kk][1].z);
        o[kk][1].w = fmaf(wk[kk], x1.w, o[kk][1].w);
      }
    }
  }

  // ---- epilogue: slab partials ----
  float* Ob = Op + (size_t)blk * NK * NC;
#pragma unroll
  for (int kk = 0; kk < 8; ++kk) {
    *(float4*)(Ob + (size_t)(kg * 8 + kk) * NC + cg * 4)       = o[kk][0];
    *(float4*)(Ob + (size_t)(kg * 8 + kk) * NC + 512 + cg * 4) = o[kk][1];
  }
  if (tid < 16) {
    MSp[(blk * 16 + tid) * 2]     = mS[tid];
    MSp[(blk * 16 + tid) * 2 + 1] = sS[tid];
  }
}

// ---------------------------------------------------------------------------
// Kernel 2: merge SLABS partials per (b,k) with max-rescale + normalize.
// grid 256 (one per (b,k)), 256 threads. All-masked rows -> denom 0 -> zeros.
// ---------------------------------------------------------------------------
template<int SLABS>
__global__ __launch_bounds__(256, 2)
void qpool_combine(const float* __restrict__ Op, const float* __restrict__ MSp,
                   float* __restrict__ Out) {
  const int bk = blockIdx.x;
  const int b = bk >> 4, k = bk & 15;
  const int tid = threadIdx.x;

  float m[SLABS], s[SLABS], f[SLABS];
  float M = -FLT_MAX;
#pragma unroll
  for (int lb = 0; lb < SLABS; ++lb) {
    m[lb] = MSp[((b * SLABS + lb) * 16 + k) * 2];
    s[lb] = MSp[((b * SLABS + lb) * 16 + k) * 2 + 1];
    M = fmaxf(M, m[lb]);
  }
  float denom = 0.f;
#pragma unroll
  for (int lb = 0; lb < SLABS; ++lb) {
    f[lb] = exp2f((m[lb] - M) * SC2);
    denom += s[lb] * f[lb];
  }
  float4 acc = make_float4(0.f, 0.f, 0.f, 0.f);
#pragma unroll
  for (int lb = 0; lb < SLABS; ++lb) {
    const float4 v = ld4(Op + ((size_t)(b * SLABS + lb) * 16 + k) * NC + tid * 4);
    acc.x = fmaf(f[lb], v.x, acc.x);
    acc.y = fmaf(f[lb], v.y, acc.y);
    acc.z = fmaf(f[lb], v.z, acc.z);
    acc.w = fmaf(f[lb], v.w, acc.w);
  }
  const float inv = denom > 0.f ? 1.f / denom : 0.f;
  acc.x *= inv; acc.y *= inv; acc.z *= inv; acc.w *= inv;
  *(float4*)(Out + (size_t)bk * NC + tid * 4) = acc;
}

extern "C" void kernel_launch(void* const* d_in, const int* in_sizes, int n_in,
                              void* d_out, int out_size, void* d_ws, size_t ws_size,
                              hipStream_t stream) {
  const float* X  = (const float*)d_in[0];
  const int*   Mk = (const int*)d_in[1];
  const float* Q  = (const float*)d_in[2];
  float* Out = (float*)d_out;

  // fast path: 512 slab partials = 33.6 MB of workspace
  const size_t need512 = ((size_t)512 * NK * NC + (size_t)512 * NK * 2) * sizeof(float);
  if (ws_size >= need512) {
    float* Op  = (float*)d_ws;
    float* MSp = Op + (size_t)512 * NK * NC;
    qpool_partial<16><<<512, 256, 0, stream>>>(X, Mk, Q, Op, MSp);
    qpool_combine<32><<<256, 256, 0, stream>>>(Op, MSp, Out);
  } else {
    float* Op  = (float*)d_ws;
    float* MSp = Op + (size_t)256 * NK * NC;
    qpool_partial<32><<<256, 256, 0, stream>>>(X, Mk, Q, Op, MSp);
    qpool_combine<16><<<256, 256, 0, stream>>>(Op, MSp, Out);
  }
}